// Round 1
// baseline (508.247 us; speedup 1.0000x reference)
//
#include <hip/hip_runtime.h>

#define H 1024
#define F 2048
#define NE 8
#define T_TOK 8192

#define BM 128
#define BN 128
#define BK 64

typedef __bf16 bf16x8 __attribute__((ext_vector_type(8)));
typedef float floatx4 __attribute__((ext_vector_type(4)));

__device__ __forceinline__ unsigned short f2bf(float f) {
    unsigned int u = __builtin_bit_cast(unsigned int, f);
    u = (u + 0x7fffu + ((u >> 16) & 1u)) >> 16;
    return (unsigned short)u;
}

// ---------------- x fp32 -> bf16 ----------------
__global__ __launch_bounds__(256) void cvt_x_kernel(const float* __restrict__ x,
                                                    unsigned short* __restrict__ xb) {
    int i = blockIdx.x * 256 + threadIdx.x;  // one float4 per thread
    float4 v = ((const float4*)x)[i];
    ushort4 o;
    o.x = f2bf(v.x); o.y = f2bf(v.y); o.z = f2bf(v.z); o.w = f2bf(v.w);
    ((ushort4*)xb)[i] = o;
}

// ---------------- transpose + convert: in[R][C] fp32 -> out[C][R] bf16, per expert z ----
__global__ __launch_bounds__(256) void transpose_cvt_kernel(const float* __restrict__ in,
                                                            unsigned short* __restrict__ out,
                                                            int R, int C) {
    __shared__ float tile[32][33];
    const size_t mat = (size_t)R * C;
    const float* ib = in + (size_t)blockIdx.z * mat;
    unsigned short* ob = out + (size_t)blockIdx.z * mat;
    int c0 = blockIdx.x * 32, r0 = blockIdx.y * 32;
    int tx = threadIdx.x, ty = threadIdx.y;  // (32,8)
#pragma unroll
    for (int j = 0; j < 4; ++j)
        tile[ty + j * 8][tx] = ib[(size_t)(r0 + ty + j * 8) * C + c0 + tx];
    __syncthreads();
#pragma unroll
    for (int j = 0; j < 4; ++j)
        ob[(size_t)(c0 + ty + j * 8) * R + r0 + tx] = f2bf(tile[tx][ty + j * 8]);
}

// ---------------- gating: fp32 logits, top-2, bucket by expert ----------------
__global__ __launch_bounds__(256) void gate_kernel(const float* __restrict__ x,
                                                   const float* __restrict__ gw,
                                                   const float* __restrict__ gb,
                                                   int* __restrict__ counts,
                                                   int* __restrict__ btok,
                                                   float* __restrict__ bw) {
    const int lane = threadIdx.x & 63;
    const int wid = threadIdx.x >> 6;
    const int t = blockIdx.x * 4 + wid;
    const float* xr = x + (size_t)t * H;
    float acc[8];
#pragma unroll
    for (int e = 0; e < 8; ++e) acc[e] = 0.f;
#pragma unroll
    for (int j = 0; j < 16; ++j) {
        int h = j * 64 + lane;
        float xv = xr[h];
        const float4* g = (const float4*)(gw + h * 8);
        float4 g0 = g[0], g1 = g[1];
        acc[0] += xv * g0.x; acc[1] += xv * g0.y;
        acc[2] += xv * g0.z; acc[3] += xv * g0.w;
        acc[4] += xv * g1.x; acc[5] += xv * g1.y;
        acc[6] += xv * g1.z; acc[7] += xv * g1.w;
    }
#pragma unroll
    for (int m = 32; m >= 1; m >>= 1) {
#pragma unroll
        for (int e = 0; e < 8; ++e) acc[e] += __shfl_xor(acc[e], m, 64);
    }
    if (lane == 0) {
        float lg[8];
#pragma unroll
        for (int e = 0; e < 8; ++e) lg[e] = acc[e] + gb[e];
        int i1 = 0; float v1 = lg[0];
#pragma unroll
        for (int e = 1; e < 8; ++e) { if (lg[e] > v1) { v1 = lg[e]; i1 = e; } }
        int i2 = -1; float v2 = -1e30f;
#pragma unroll
        for (int e = 0; e < 8; ++e) { if (e != i1 && lg[e] > v2) { v2 = lg[e]; i2 = e; } }
        float ed = expf(v2 - v1);
        float wA = 1.f / (1.f + ed);
        float wB = ed / (1.f + ed);
        int p = atomicAdd(&counts[i1], 1);
        btok[i1 * T_TOK + p] = t; bw[i1 * T_TOK + p] = wA;
        p = atomicAdd(&counts[i2], 1);
        btok[i2 * T_TOK + p] = t; bw[i2 * T_TOK + p] = wB;
    }
}

__global__ void offsets_kernel(const int* __restrict__ counts, int* __restrict__ offs) {
    if (threadIdx.x == 0) {
        int s = 0;
#pragma unroll
        for (int e = 0; e < NE; ++e) { offs[e] = s; s += counts[e]; }
    }
}

// ---------------- FFN layer 1: h = relu(x_gather @ w1 + b1), bf16 MFMA ----------------
__global__ __launch_bounds__(256, 2) void ffn1_kernel(const unsigned short* __restrict__ xb,
                                                      const unsigned short* __restrict__ w1t,
                                                      const float* __restrict__ b1,
                                                      const int* __restrict__ counts,
                                                      const int* __restrict__ offs,
                                                      const int* __restrict__ btok,
                                                      unsigned short* __restrict__ hbuf) {
    const int e = blockIdx.z;
    const int cnt = counts[e];
    const int by = blockIdx.y;
    if (by * BM >= cnt) return;
    const int n0 = blockIdx.x * BN;
    const int off_e = offs[e];

    __shared__ __align__(16) char smem[32768];
    char* As = smem;
    char* Bs = smem + 16384;

    const int tid = threadIdx.x;
    int rowA[4], c16A[4], tokA[4];
#pragma unroll
    for (int i = 0; i < 4; ++i) {
        int q = tid + i * 256;
        rowA[i] = q >> 3;
        c16A[i] = q & 7;
        int m = by * BM + rowA[i];
        tokA[i] = btok[e * T_TOK + min(m, cnt - 1)];
    }

    floatx4 acc[4][4];
#pragma unroll
    for (int i = 0; i < 4; ++i)
#pragma unroll
        for (int j = 0; j < 4; ++j)
#pragma unroll
            for (int r = 0; r < 4; ++r) acc[i][j][r] = 0.f;

    const int lane = tid & 63, wid = tid >> 6;
    const int wm = (wid >> 1) * 64, wn = (wid & 1) * 64;

    bf16x8 ar[4], br[4];
    auto load_tiles = [&](int kt) {
        const int k0 = kt * BK;
#pragma unroll
        for (int i = 0; i < 4; ++i) {
            ar[i] = *(const bf16x8*)(xb + (size_t)tokA[i] * H + k0 + c16A[i] * 8);
            br[i] = *(const bf16x8*)(w1t + ((size_t)e * F + n0 + rowA[i]) * H + k0 + c16A[i] * 8);
        }
    };

    const int NT = H / BK;  // 16
    load_tiles(0);
    for (int kt = 0; kt < NT; ++kt) {
#pragma unroll
        for (int i = 0; i < 4; ++i) {
            int wb = rowA[i] * 128 + ((c16A[i] ^ (rowA[i] & 7)) * 16);
            *(bf16x8*)(As + wb) = ar[i];
            *(bf16x8*)(Bs + wb) = br[i];
        }
        __syncthreads();
        if (kt + 1 < NT) load_tiles(kt + 1);
#pragma unroll
        for (int kk = 0; kk < 2; ++kk) {
            bf16x8 af[4], bfr[4];
#pragma unroll
            for (int i = 0; i < 4; ++i) {
                int rA = wm + i * 16 + (lane & 15);
                af[i] = *(const bf16x8*)(As + rA * 128 + (((kk * 4 + (lane >> 4)) ^ (rA & 7)) * 16));
                int rB = wn + i * 16 + (lane & 15);
                bfr[i] = *(const bf16x8*)(Bs + rB * 128 + (((kk * 4 + (lane >> 4)) ^ (rB & 7)) * 16));
            }
#pragma unroll
            for (int i = 0; i < 4; ++i)
#pragma unroll
                for (int j = 0; j < 4; ++j)
                    acc[i][j] = __builtin_amdgcn_mfma_f32_16x16x32_bf16(af[i], bfr[j], acc[i][j], 0, 0, 0);
        }
        __syncthreads();
    }

#pragma unroll
    for (int i = 0; i < 4; ++i) {
        int mrow = wm + i * 16 + (lane >> 4) * 4;
#pragma unroll
        for (int r = 0; r < 4; ++r) {
            int mg = by * BM + mrow + r;
            if (mg < cnt) {
                size_t hrow = (size_t)(off_e + mg) * F;
#pragma unroll
                for (int j = 0; j < 4; ++j) {
                    int ng = n0 + wn + j * 16 + (lane & 15);
                    float v = acc[i][j][r] + b1[e * F + ng];
                    v = fmaxf(v, 0.f);
                    hbuf[hrow + ng] = f2bf(v);
                }
            }
        }
    }
}

// ---------------- FFN layer 2: out += w * (h @ w2 + b2) ----------------
__global__ __launch_bounds__(256, 2) void ffn2_kernel(const unsigned short* __restrict__ hbuf,
                                                      const unsigned short* __restrict__ w2t,
                                                      const float* __restrict__ b2,
                                                      const int* __restrict__ counts,
                                                      const int* __restrict__ offs,
                                                      const int* __restrict__ btok,
                                                      const float* __restrict__ bw,
                                                      float* __restrict__ out) {
    const int e = blockIdx.z;
    const int cnt = counts[e];
    const int by = blockIdx.y;
    if (by * BM >= cnt) return;
    const int n0 = blockIdx.x * BN;
    const int off_e = offs[e];

    __shared__ __align__(16) char smem[32768];
    char* As = smem;
    char* Bs = smem + 16384;

    const int tid = threadIdx.x;
    int rowA[4], c16A[4], arow[4];
#pragma unroll
    for (int i = 0; i < 4; ++i) {
        int q = tid + i * 256;
        rowA[i] = q >> 3;
        c16A[i] = q & 7;
        int m = by * BM + rowA[i];
        arow[i] = off_e + min(m, cnt - 1);
    }

    floatx4 acc[4][4];
#pragma unroll
    for (int i = 0; i < 4; ++i)
#pragma unroll
        for (int j = 0; j < 4; ++j)
#pragma unroll
            for (int r = 0; r < 4; ++r) acc[i][j][r] = 0.f;

    const int lane = tid & 63, wid = tid >> 6;
    const int wm = (wid >> 1) * 64, wn = (wid & 1) * 64;

    bf16x8 ar[4], br[4];
    auto load_tiles = [&](int kt) {
        const int k0 = kt * BK;
#pragma unroll
        for (int i = 0; i < 4; ++i) {
            ar[i] = *(const bf16x8*)(hbuf + (size_t)arow[i] * F + k0 + c16A[i] * 8);
            br[i] = *(const bf16x8*)(w2t + ((size_t)e * H + n0 + rowA[i]) * F + k0 + c16A[i] * 8);
        }
    };

    const int NT = F / BK;  // 32
    load_tiles(0);
    for (int kt = 0; kt < NT; ++kt) {
#pragma unroll
        for (int i = 0; i < 4; ++i) {
            int wb = rowA[i] * 128 + ((c16A[i] ^ (rowA[i] & 7)) * 16);
            *(bf16x8*)(As + wb) = ar[i];
            *(bf16x8*)(Bs + wb) = br[i];
        }
        __syncthreads();
        if (kt + 1 < NT) load_tiles(kt + 1);
#pragma unroll
        for (int kk = 0; kk < 2; ++kk) {
            bf16x8 af[4], bfr[4];
#pragma unroll
            for (int i = 0; i < 4; ++i) {
                int rA = wm + i * 16 + (lane & 15);
                af[i] = *(const bf16x8*)(As + rA * 128 + (((kk * 4 + (lane >> 4)) ^ (rA & 7)) * 16));
                int rB = wn + i * 16 + (lane & 15);
                bfr[i] = *(const bf16x8*)(Bs + rB * 128 + (((kk * 4 + (lane >> 4)) ^ (rB & 7)) * 16));
            }
#pragma unroll
            for (int i = 0; i < 4; ++i)
#pragma unroll
                for (int j = 0; j < 4; ++j)
                    acc[i][j] = __builtin_amdgcn_mfma_f32_16x16x32_bf16(af[i], bfr[j], acc[i][j], 0, 0, 0);
        }
        __syncthreads();
    }

#pragma unroll
    for (int i = 0; i < 4; ++i) {
        int mrow = wm + i * 16 + (lane >> 4) * 4;
#pragma unroll
        for (int r = 0; r < 4; ++r) {
            int mg = by * BM + mrow + r;
            if (mg < cnt) {
                int tok = btok[e * T_TOK + mg];
                float w = bw[e * T_TOK + mg];
#pragma unroll
                for (int j = 0; j < 4; ++j) {
                    int ng = n0 + wn + j * 16 + (lane & 15);
                    float v = (acc[i][j][r] + b2[e * H + ng]) * w;
                    atomicAdd(&out[(size_t)tok * H + ng], v);
                }
            }
        }
    }
}

extern "C" void kernel_launch(void* const* d_in, const int* in_sizes, int n_in,
                              void* d_out, int out_size, void* d_ws, size_t ws_size,
                              hipStream_t stream) {
    (void)in_sizes; (void)n_in; (void)out_size; (void)ws_size;
    const float* x  = (const float*)d_in[0];
    const float* gw = (const float*)d_in[1];
    const float* gb = (const float*)d_in[2];
    const float* w1 = (const float*)d_in[3];
    const float* b1 = (const float*)d_in[4];
    const float* w2 = (const float*)d_in[5];
    const float* b2 = (const float*)d_in[6];
    float* out = (float*)d_out;

    char* ws = (char*)d_ws;
    unsigned short* xb   = (unsigned short*)(ws);                        // 16 MB
    unsigned short* w1t  = (unsigned short*)(ws + (16ull << 20));        // 32 MB
    unsigned short* w2t  = (unsigned short*)(ws + (48ull << 20));        // 32 MB
    unsigned short* hbuf = (unsigned short*)(ws + (80ull << 20));        // 64 MB
    int*   btok   = (int*)(ws + (144ull << 20));                         // 256 KB
    float* bwgt   = (float*)(ws + (144ull << 20) + (size_t)T_TOK * NE * 4);
    int*   counts = (int*)(ws + (145ull << 20));
    int*   offs   = counts + 8;

    hipMemsetAsync(counts, 0, 8 * sizeof(int), stream);
    hipMemsetAsync(out, 0, (size_t)T_TOK * H * sizeof(float), stream);

    cvt_x_kernel<<<(T_TOK * H / 4) / 256, 256, 0, stream>>>(x, xb);
    transpose_cvt_kernel<<<dim3(F / 32, H / 32, NE), dim3(32, 8), 0, stream>>>(w1, w1t, H, F);
    transpose_cvt_kernel<<<dim3(H / 32, F / 32, NE), dim3(32, 8), 0, stream>>>(w2, w2t, F, H);
    gate_kernel<<<T_TOK / 4, 256, 0, stream>>>(x, gw, gb, counts, btok, bwgt);
    offsets_kernel<<<1, 64, 0, stream>>>(counts, offs);
    ffn1_kernel<<<dim3(F / BN, T_TOK / BM, NE), 256, 0, stream>>>(xb, w1t, b1, counts, offs, btok, hbuf);
    ffn2_kernel<<<dim3(H / BN, T_TOK / BM, NE), 256, 0, stream>>>(hbuf, w2t, b2, counts, offs, btok, bwgt, out);
}

// Round 2
// 332.879 us; speedup vs baseline: 1.5268x; 1.5268x over previous
//
#include <hip/hip_runtime.h>

#define H 1024
#define F 2048
#define NE 8
#define T_TOK 8192

#define BM 128
#define BN 128
#define BK 64

typedef __bf16 bf16x8 __attribute__((ext_vector_type(8)));
typedef float floatx4 __attribute__((ext_vector_type(4)));

__device__ __forceinline__ unsigned short f2bf(float f) {
    unsigned int u = __builtin_bit_cast(unsigned int, f);
    u = (u + 0x7fffu + ((u >> 16) & 1u)) >> 16;
    return (unsigned short)u;
}

// ---------------- x fp32 -> bf16 ----------------
__global__ __launch_bounds__(256) void cvt_x_kernel(const float* __restrict__ x,
                                                    unsigned short* __restrict__ xb) {
    int i = blockIdx.x * 256 + threadIdx.x;  // one float4 per thread
    float4 v = ((const float4*)x)[i];
    ushort4 o;
    o.x = f2bf(v.x); o.y = f2bf(v.y); o.z = f2bf(v.z); o.w = f2bf(v.w);
    ((ushort4*)xb)[i] = o;
}

// ---------------- transpose + convert: in[R][C] fp32 -> out[C][R] bf16, per expert z ----
__global__ __launch_bounds__(256) void transpose_cvt_kernel(const float* __restrict__ in,
                                                            unsigned short* __restrict__ out,
                                                            int R, int C) {
    __shared__ float tile[32][33];
    const size_t mat = (size_t)R * C;
    const float* ib = in + (size_t)blockIdx.z * mat;
    unsigned short* ob = out + (size_t)blockIdx.z * mat;
    int c0 = blockIdx.x * 32, r0 = blockIdx.y * 32;
    int tx = threadIdx.x, ty = threadIdx.y;  // (32,8)
#pragma unroll
    for (int j = 0; j < 4; ++j)
        tile[ty + j * 8][tx] = ib[(size_t)(r0 + ty + j * 8) * C + c0 + tx];
    __syncthreads();
#pragma unroll
    for (int j = 0; j < 4; ++j)
        ob[(size_t)(c0 + ty + j * 8) * R + r0 + tx] = f2bf(tile[tx][ty + j * 8]);
}

// ---------------- gating phase A: fp32 logits, per-token top-2 (NO atomics) ----------------
__global__ __launch_bounds__(256) void gate_kernel(const float* __restrict__ x,
                                                   const float* __restrict__ gw,
                                                   const float* __restrict__ gb,
                                                   int* __restrict__ top_i,
                                                   float* __restrict__ top_w) {
    const int lane = threadIdx.x & 63;
    const int wid = threadIdx.x >> 6;
    const int t = blockIdx.x * 4 + wid;
    const float* xr = x + (size_t)t * H;
    float acc[8];
#pragma unroll
    for (int e = 0; e < 8; ++e) acc[e] = 0.f;
#pragma unroll
    for (int j = 0; j < 16; ++j) {
        int h = j * 64 + lane;
        float xv = xr[h];
        const float4* g = (const float4*)(gw + h * 8);
        float4 g0 = g[0], g1 = g[1];
        acc[0] += xv * g0.x; acc[1] += xv * g0.y;
        acc[2] += xv * g0.z; acc[3] += xv * g0.w;
        acc[4] += xv * g1.x; acc[5] += xv * g1.y;
        acc[6] += xv * g1.z; acc[7] += xv * g1.w;
    }
#pragma unroll
    for (int m = 32; m >= 1; m >>= 1) {
#pragma unroll
        for (int e = 0; e < 8; ++e) acc[e] += __shfl_xor(acc[e], m, 64);
    }
    if (lane == 0) {
        float lg[8];
#pragma unroll
        for (int e = 0; e < 8; ++e) lg[e] = acc[e] + gb[e];
        int i1 = 0; float v1 = lg[0];
#pragma unroll
        for (int e = 1; e < 8; ++e) { if (lg[e] > v1) { v1 = lg[e]; i1 = e; } }
        int i2 = -1; float v2 = -1e30f;
#pragma unroll
        for (int e = 0; e < 8; ++e) { if (e != i1 && lg[e] > v2) { v2 = lg[e]; i2 = e; } }
        float ed = expf(v2 - v1);
        float wA = 1.f / (1.f + ed);
        float wB = ed / (1.f + ed);
        top_i[t * 2] = i1; top_i[t * 2 + 1] = i2;
        top_w[t * 2] = wA; top_w[t * 2 + 1] = wB;
    }
}

// ---------------- gating phase B: deterministic compaction (token order) ----------------
__global__ __launch_bounds__(1024) void compact_kernel(const int* __restrict__ top_i,
                                                       const float* __restrict__ top_w,
                                                       int* __restrict__ counts,
                                                       int* __restrict__ btok,
                                                       float* __restrict__ bw) {
    const int e = blockIdx.x;
    const int tid = threadIdx.x;
    const int lane = tid & 63, w = tid >> 6;
    __shared__ int wsums[16];
    int base = 0;
    for (int c = 0; c < T_TOK / 1024; ++c) {
        int t = c * 1024 + tid;
        int i1 = top_i[t * 2], i2 = top_i[t * 2 + 1];
        bool f1 = (i1 == e), f2 = (i2 == e);
        bool f = f1 || f2;
        unsigned long long m = __ballot(f);
        int mypos = __popcll(m & ((1ull << lane) - 1ull));
        if (lane == 0) wsums[w] = __popcll(m);
        __syncthreads();
        int wpre = 0, tot = 0;
#pragma unroll
        for (int i = 0; i < 16; ++i) { int s = wsums[i]; if (i < w) wpre += s; tot += s; }
        if (f) {
            int pos = base + wpre + mypos;
            btok[e * T_TOK + pos] = t;
            bw[e * T_TOK + pos] = f1 ? top_w[t * 2] : top_w[t * 2 + 1];
        }
        base += tot;
        __syncthreads();
    }
    if (tid == 0) counts[e] = base;
}

__global__ void offsets_kernel(const int* __restrict__ counts, int* __restrict__ offs) {
    if (threadIdx.x == 0) {
        int s = 0;
#pragma unroll
        for (int e = 0; e < NE; ++e) { offs[e] = s; s += counts[e]; }
    }
}

// ---------------- FFN layer 1: h = relu(x_gather @ w1 + b1), bf16 MFMA ----------------
__global__ __launch_bounds__(256, 2) void ffn1_kernel(const unsigned short* __restrict__ xb,
                                                      const unsigned short* __restrict__ w1t,
                                                      const float* __restrict__ b1,
                                                      const int* __restrict__ counts,
                                                      const int* __restrict__ offs,
                                                      const int* __restrict__ btok,
                                                      unsigned short* __restrict__ hbuf) {
    const int e = blockIdx.z;
    const int cnt = counts[e];
    const int by = blockIdx.y;
    if (by * BM >= cnt) return;
    const int n0 = blockIdx.x * BN;
    const int off_e = offs[e];

    __shared__ __align__(16) char smem[32768];
    char* As = smem;
    char* Bs = smem + 16384;

    const int tid = threadIdx.x;
    int rowA[4], c16A[4], tokA[4];
#pragma unroll
    for (int i = 0; i < 4; ++i) {
        int q = tid + i * 256;
        rowA[i] = q >> 3;
        c16A[i] = q & 7;
        int m = by * BM + rowA[i];
        tokA[i] = btok[e * T_TOK + min(m, cnt - 1)];
    }

    floatx4 acc[4][4];
#pragma unroll
    for (int i = 0; i < 4; ++i)
#pragma unroll
        for (int j = 0; j < 4; ++j)
#pragma unroll
            for (int r = 0; r < 4; ++r) acc[i][j][r] = 0.f;

    const int lane = tid & 63, wid = tid >> 6;
    const int wm = (wid >> 1) * 64, wn = (wid & 1) * 64;

    bf16x8 ar[4], br[4];
    auto load_tiles = [&](int kt) {
        const int k0 = kt * BK;
#pragma unroll
        for (int i = 0; i < 4; ++i) {
            ar[i] = *(const bf16x8*)(xb + (size_t)tokA[i] * H + k0 + c16A[i] * 8);
            br[i] = *(const bf16x8*)(w1t + ((size_t)e * F + n0 + rowA[i]) * H + k0 + c16A[i] * 8);
        }
    };

    const int NT = H / BK;  // 16
    load_tiles(0);
    for (int kt = 0; kt < NT; ++kt) {
#pragma unroll
        for (int i = 0; i < 4; ++i) {
            int wb = rowA[i] * 128 + ((c16A[i] ^ (rowA[i] & 7)) * 16);
            *(bf16x8*)(As + wb) = ar[i];
            *(bf16x8*)(Bs + wb) = br[i];
        }
        __syncthreads();
        if (kt + 1 < NT) load_tiles(kt + 1);
#pragma unroll
        for (int kk = 0; kk < 2; ++kk) {
            bf16x8 af[4], bfr[4];
#pragma unroll
            for (int i = 0; i < 4; ++i) {
                int rA = wm + i * 16 + (lane & 15);
                af[i] = *(const bf16x8*)(As + rA * 128 + (((kk * 4 + (lane >> 4)) ^ (rA & 7)) * 16));
                int rB = wn + i * 16 + (lane & 15);
                bfr[i] = *(const bf16x8*)(Bs + rB * 128 + (((kk * 4 + (lane >> 4)) ^ (rB & 7)) * 16));
            }
#pragma unroll
            for (int i = 0; i < 4; ++i)
#pragma unroll
                for (int j = 0; j < 4; ++j)
                    acc[i][j] = __builtin_amdgcn_mfma_f32_16x16x32_bf16(af[i], bfr[j], acc[i][j], 0, 0, 0);
        }
        __syncthreads();
    }

#pragma unroll
    for (int i = 0; i < 4; ++i) {
        int mrow = wm + i * 16 + (lane >> 4) * 4;
#pragma unroll
        for (int r = 0; r < 4; ++r) {
            int mg = by * BM + mrow + r;
            if (mg < cnt) {
                size_t hrow = (size_t)(off_e + mg) * F;
#pragma unroll
                for (int j = 0; j < 4; ++j) {
                    int ng = n0 + wn + j * 16 + (lane & 15);
                    float v = acc[i][j][r] + b1[e * F + ng];
                    v = fmaxf(v, 0.f);
                    hbuf[hrow + ng] = f2bf(v);
                }
            }
        }
    }
}

// ---------------- FFN layer 2: out += w * (h @ w2 + b2) ----------------
__global__ __launch_bounds__(256, 2) void ffn2_kernel(const unsigned short* __restrict__ hbuf,
                                                      const unsigned short* __restrict__ w2t,
                                                      const float* __restrict__ b2,
                                                      const int* __restrict__ counts,
                                                      const int* __restrict__ offs,
                                                      const int* __restrict__ btok,
                                                      const float* __restrict__ bw,
                                                      float* __restrict__ out) {
    const int e = blockIdx.z;
    const int cnt = counts[e];
    const int by = blockIdx.y;
    if (by * BM >= cnt) return;
    const int n0 = blockIdx.x * BN;
    const int off_e = offs[e];

    __shared__ __align__(16) char smem[32768];
    char* As = smem;
    char* Bs = smem + 16384;

    const int tid = threadIdx.x;
    int rowA[4], c16A[4], arow[4];
#pragma unroll
    for (int i = 0; i < 4; ++i) {
        int q = tid + i * 256;
        rowA[i] = q >> 3;
        c16A[i] = q & 7;
        int m = by * BM + rowA[i];
        arow[i] = off_e + min(m, cnt - 1);
    }

    floatx4 acc[4][4];
#pragma unroll
    for (int i = 0; i < 4; ++i)
#pragma unroll
        for (int j = 0; j < 4; ++j)
#pragma unroll
            for (int r = 0; r < 4; ++r) acc[i][j][r] = 0.f;

    const int lane = tid & 63, wid = tid >> 6;
    const int wm = (wid >> 1) * 64, wn = (wid & 1) * 64;

    bf16x8 ar[4], br[4];
    auto load_tiles = [&](int kt) {
        const int k0 = kt * BK;
#pragma unroll
        for (int i = 0; i < 4; ++i) {
            ar[i] = *(const bf16x8*)(hbuf + (size_t)arow[i] * F + k0 + c16A[i] * 8);
            br[i] = *(const bf16x8*)(w2t + ((size_t)e * H + n0 + rowA[i]) * F + k0 + c16A[i] * 8);
        }
    };

    const int NT = F / BK;  // 32
    load_tiles(0);
    for (int kt = 0; kt < NT; ++kt) {
#pragma unroll
        for (int i = 0; i < 4; ++i) {
            int wb = rowA[i] * 128 + ((c16A[i] ^ (rowA[i] & 7)) * 16);
            *(bf16x8*)(As + wb) = ar[i];
            *(bf16x8*)(Bs + wb) = br[i];
        }
        __syncthreads();
        if (kt + 1 < NT) load_tiles(kt + 1);
#pragma unroll
        for (int kk = 0; kk < 2; ++kk) {
            bf16x8 af[4], bfr[4];
#pragma unroll
            for (int i = 0; i < 4; ++i) {
                int rA = wm + i * 16 + (lane & 15);
                af[i] = *(const bf16x8*)(As + rA * 128 + (((kk * 4 + (lane >> 4)) ^ (rA & 7)) * 16));
                int rB = wn + i * 16 + (lane & 15);
                bfr[i] = *(const bf16x8*)(Bs + rB * 128 + (((kk * 4 + (lane >> 4)) ^ (rB & 7)) * 16));
            }
#pragma unroll
            for (int i = 0; i < 4; ++i)
#pragma unroll
                for (int j = 0; j < 4; ++j)
                    acc[i][j] = __builtin_amdgcn_mfma_f32_16x16x32_bf16(af[i], bfr[j], acc[i][j], 0, 0, 0);
        }
        __syncthreads();
    }

#pragma unroll
    for (int i = 0; i < 4; ++i) {
        int mrow = wm + i * 16 + (lane >> 4) * 4;
#pragma unroll
        for (int r = 0; r < 4; ++r) {
            int mg = by * BM + mrow + r;
            if (mg < cnt) {
                int tok = btok[e * T_TOK + mg];
                float w = bw[e * T_TOK + mg];
#pragma unroll
                for (int j = 0; j < 4; ++j) {
                    int ng = n0 + wn + j * 16 + (lane & 15);
                    float v = (acc[i][j][r] + b2[e * H + ng]) * w;
                    atomicAdd(&out[(size_t)tok * H + ng], v);
                }
            }
        }
    }
}

extern "C" void kernel_launch(void* const* d_in, const int* in_sizes, int n_in,
                              void* d_out, int out_size, void* d_ws, size_t ws_size,
                              hipStream_t stream) {
    (void)in_sizes; (void)n_in; (void)out_size; (void)ws_size;
    const float* x  = (const float*)d_in[0];
    const float* gw = (const float*)d_in[1];
    const float* gb = (const float*)d_in[2];
    const float* w1 = (const float*)d_in[3];
    const float* b1 = (const float*)d_in[4];
    const float* w2 = (const float*)d_in[5];
    const float* b2 = (const float*)d_in[6];
    float* out = (float*)d_out;

    char* ws = (char*)d_ws;
    unsigned short* xb   = (unsigned short*)(ws);                        // 16 MB
    unsigned short* w1t  = (unsigned short*)(ws + (16ull << 20));        // 32 MB
    unsigned short* w2t  = (unsigned short*)(ws + (48ull << 20));        // 32 MB
    unsigned short* hbuf = (unsigned short*)(ws + (80ull << 20));        // 64 MB
    int*   btok   = (int*)(ws + (144ull << 20));                         // 256 KB
    float* bwgt   = (float*)(ws + (144ull << 20) + (size_t)T_TOK * NE * 4);
    int*   counts = (int*)(ws + (145ull << 20));
    int*   offs   = counts + 8;
    int*   top_i  = (int*)(ws + (145ull << 20) + 4096);                  // 64 KB
    float* top_w  = (float*)(ws + (145ull << 20) + 4096 + 65536);        // 64 KB

    hipMemsetAsync(out, 0, (size_t)T_TOK * H * sizeof(float), stream);

    cvt_x_kernel<<<(T_TOK * H / 4) / 256, 256, 0, stream>>>(x, xb);
    transpose_cvt_kernel<<<dim3(F / 32, H / 32, NE), dim3(32, 8), 0, stream>>>(w1, w1t, H, F);
    transpose_cvt_kernel<<<dim3(H / 32, F / 32, NE), dim3(32, 8), 0, stream>>>(w2, w2t, F, H);
    gate_kernel<<<T_TOK / 4, 256, 0, stream>>>(x, gw, gb, top_i, top_w);
    compact_kernel<<<NE, 1024, 0, stream>>>(top_i, top_w, counts, btok, bwgt);
    offsets_kernel<<<1, 64, 0, stream>>>(counts, offs);
    ffn1_kernel<<<dim3(F / BN, T_TOK / BM, NE), 256, 0, stream>>>(xb, w1t, b1, counts, offs, btok, hbuf);
    ffn2_kernel<<<dim3(H / BN, T_TOK / BM, NE), 256, 0, stream>>>(hbuf, w2t, b2, counts, offs, btok, bwgt, out);
}

// Round 4
// 262.386 us; speedup vs baseline: 1.9370x; 1.2687x over previous
//
#include <hip/hip_runtime.h>

#define H 1024
#define F 2048
#define NE 8
#define T_TOK 8192

#define BM 128
#define BN 128
#define BK 64

typedef __bf16 bf16x8 __attribute__((ext_vector_type(8)));
typedef float floatx4 __attribute__((ext_vector_type(4)));

__device__ __forceinline__ unsigned short f2bf(float f) {
    unsigned int u = __builtin_bit_cast(unsigned int, f);
    u = (u + 0x7fffu + ((u >> 16) & 1u)) >> 16;
    return (unsigned short)u;
}
__device__ __forceinline__ float bf2f(unsigned short u) {
    unsigned int x = ((unsigned int)u) << 16;
    return __builtin_bit_cast(float, x);
}

// async 16B global -> LDS (linear dest: wave-uniform base + lane*16)
__device__ __forceinline__ void gload16(const unsigned short* g, void* l) {
    __builtin_amdgcn_global_load_lds(
        (const __attribute__((address_space(1))) unsigned int*)g,
        (__attribute__((address_space(3))) unsigned int*)l,
        16, 0, 0);
}

// ---------------- x fp32 -> bf16 ----------------
__global__ __launch_bounds__(256) void cvt_x_kernel(const float* __restrict__ x,
                                                    unsigned short* __restrict__ xb) {
    int i = blockIdx.x * 256 + threadIdx.x;
    float4 v = ((const float4*)x)[i];
    ushort4 o;
    o.x = f2bf(v.x); o.y = f2bf(v.y); o.z = f2bf(v.z); o.w = f2bf(v.w);
    ((ushort4*)xb)[i] = o;
}

// ---------------- transpose + convert: in[R][C] fp32 -> out[C][R] bf16 ----------------
__global__ __launch_bounds__(256) void transpose_cvt_kernel(const float* __restrict__ in,
                                                            unsigned short* __restrict__ out,
                                                            int R, int C) {
    __shared__ float tile[32][33];
    const size_t mat = (size_t)R * C;
    const float* ib = in + (size_t)blockIdx.z * mat;
    unsigned short* ob = out + (size_t)blockIdx.z * mat;
    int c0 = blockIdx.x * 32, r0 = blockIdx.y * 32;
    int tx = threadIdx.x, ty = threadIdx.y;  // (32,8)
#pragma unroll
    for (int j = 0; j < 4; ++j)
        tile[ty + j * 8][tx] = ib[(size_t)(r0 + ty + j * 8) * C + c0 + tx];
    __syncthreads();
#pragma unroll
    for (int j = 0; j < 4; ++j)
        ob[(size_t)(c0 + ty + j * 8) * R + r0 + tx] = f2bf(tile[tx][ty + j * 8]);
}

// ---------------- gating phase A: fp32 logits, per-token top-2 ----------------
__global__ __launch_bounds__(256) void gate_kernel(const float* __restrict__ x,
                                                   const float* __restrict__ gw,
                                                   const float* __restrict__ gb,
                                                   int* __restrict__ top_i,
                                                   float* __restrict__ top_w) {
    const int lane = threadIdx.x & 63;
    const int wid = threadIdx.x >> 6;
    const int t = blockIdx.x * 4 + wid;
    const float* xr = x + (size_t)t * H;
    float acc[8];
#pragma unroll
    for (int e = 0; e < 8; ++e) acc[e] = 0.f;
#pragma unroll
    for (int j = 0; j < 16; ++j) {
        int h = j * 64 + lane;
        float xv = xr[h];
        const float4* g = (const float4*)(gw + h * 8);
        float4 g0 = g[0], g1 = g[1];
        acc[0] += xv * g0.x; acc[1] += xv * g0.y;
        acc[2] += xv * g0.z; acc[3] += xv * g0.w;
        acc[4] += xv * g1.x; acc[5] += xv * g1.y;
        acc[6] += xv * g1.z; acc[7] += xv * g1.w;
    }
#pragma unroll
    for (int m = 32; m >= 1; m >>= 1) {
#pragma unroll
        for (int e = 0; e < 8; ++e) acc[e] += __shfl_xor(acc[e], m, 64);
    }
    if (lane == 0) {
        float lg[8];
#pragma unroll
        for (int e = 0; e < 8; ++e) lg[e] = acc[e] + gb[e];
        int i1 = 0; float v1 = lg[0];
#pragma unroll
        for (int e = 1; e < 8; ++e) { if (lg[e] > v1) { v1 = lg[e]; i1 = e; } }
        int i2 = -1; float v2 = -1e30f;
#pragma unroll
        for (int e = 0; e < 8; ++e) { if (e != i1 && lg[e] > v2) { v2 = lg[e]; i2 = e; } }
        float ed = expf(v2 - v1);
        float wA = 1.f / (1.f + ed);
        float wB = ed / (1.f + ed);
        top_i[t * 2] = i1; top_i[t * 2 + 1] = i2;
        top_w[t * 2] = wA; top_w[t * 2 + 1] = wB;
    }
}

// ---------------- gating phase B: deterministic compaction + inverse map ----------------
__global__ __launch_bounds__(1024) void compact_kernel(const int* __restrict__ top_i,
                                                       const float* __restrict__ top_w,
                                                       int* __restrict__ counts,
                                                       int* __restrict__ btok,
                                                       float* __restrict__ bw,
                                                       int* __restrict__ inv) {
    const int e = blockIdx.x;
    const int tid = threadIdx.x;
    const int lane = tid & 63, w = tid >> 6;
    __shared__ int wsums[16];
    int base = 0;
    for (int c = 0; c < T_TOK / 1024; ++c) {
        int t = c * 1024 + tid;
        int i1 = top_i[t * 2], i2 = top_i[t * 2 + 1];
        bool f1 = (i1 == e), f2 = (i2 == e);
        bool f = f1 || f2;
        unsigned long long m = __ballot(f);
        int mypos = __popcll(m & ((1ull << lane) - 1ull));
        if (lane == 0) wsums[w] = __popcll(m);
        __syncthreads();
        int wpre = 0, tot = 0;
#pragma unroll
        for (int i = 0; i < 16; ++i) { int s = wsums[i]; if (i < w) wpre += s; tot += s; }
        if (f) {
            int pos = base + wpre + mypos;
            btok[e * T_TOK + pos] = t;
            bw[e * T_TOK + pos] = f1 ? top_w[t * 2] : top_w[t * 2 + 1];
            inv[t * 2 + (f1 ? 0 : 1)] = (e << 16) | pos;
        }
        base += tot;
        __syncthreads();
    }
    if (tid == 0) counts[e] = base;
}

__global__ void offsets_kernel(const int* __restrict__ counts, int* __restrict__ offs) {
    if (threadIdx.x == 0) {
        int s = 0;
#pragma unroll
        for (int e = 0; e < NE; ++e) { offs[e] = s; s += counts[e]; }
    }
}

// ---------------- FFN layer 1: h = relu(x_gather @ w1 + b1) ----------------
__global__ __launch_bounds__(256, 2) void ffn1_kernel(const unsigned short* __restrict__ xb,
                                                      const unsigned short* __restrict__ w1t,
                                                      const float* __restrict__ b1,
                                                      const int* __restrict__ counts,
                                                      const int* __restrict__ offs,
                                                      const int* __restrict__ btok,
                                                      unsigned short* __restrict__ hbuf) {
    // XCD-chunked decode: expert == XCD; within expert bx fastest
    const int orig = blockIdx.x;                 // grid = 8192
    const int logical = (orig & 7) * 1024 + (orig >> 3);
    const int e = logical >> 10;
    const int rem = logical & 1023;
    const int by = rem >> 4;
    const int bx = rem & 15;
    const int cnt = counts[e];
    if (by * BM >= cnt) return;
    const int n0 = bx * BN;
    const int off_e = offs[e];

    __shared__ __align__(16) char smem[65536];

    const int tid = threadIdx.x;
    const int lane = tid & 63, wid = tid >> 6;
    const int csrc = (lane & 7) ^ (lane >> 3);   // pre-swizzled source chunk
    const int rloc = lane >> 3;                  // row within 8-row segment

    int tokA[4];
#pragma unroll
    for (int i = 0; i < 4; ++i) {
        int r = wid * 32 + i * 8 + rloc;
        tokA[i] = btok[e * T_TOK + min(by * BM + r, cnt - 1)];
    }

    floatx4 acc[4][4];
#pragma unroll
    for (int i = 0; i < 4; ++i)
#pragma unroll
        for (int j = 0; j < 4; ++j)
#pragma unroll
            for (int r = 0; r < 4; ++r) acc[i][j][r] = 0.f;

    const int wm = (wid >> 1) * 64, wn = (wid & 1) * 64;

    auto stage = [&](int boff, int kt) {
        const int k0 = kt * BK;
#pragma unroll
        for (int i = 0; i < 4; ++i) {
            int seg = wid * 32 + i * 8;
            gload16(xb + (size_t)tokA[i] * H + k0 + csrc * 8, smem + boff + seg * 128);
            gload16(w1t + ((size_t)e * F + n0 + seg + rloc) * H + k0 + csrc * 8,
                    smem + boff + 16384 + seg * 128);
        }
    };

    const int NT = H / BK;  // 16
    stage(0, 0);
    int cur = 0;
    for (int kt = 0; kt < NT; ++kt) {
        const int boff = cur * 32768;
        __syncthreads();                         // drains vmcnt: buf[cur] ready
        if (kt + 1 < NT) stage(boff ^ 32768, kt + 1);  // async prefetch under compute
#pragma unroll
        for (int kk = 0; kk < 2; ++kk) {
            bf16x8 af[4], bfr[4];
#pragma unroll
            for (int i = 0; i < 4; ++i) {
                int rA = wm + i * 16 + (lane & 15);
                af[i] = *(const bf16x8*)(smem + boff + rA * 128 + (((kk * 4 + (lane >> 4)) ^ (rA & 7)) * 16));
                int rB = wn + i * 16 + (lane & 15);
                bfr[i] = *(const bf16x8*)(smem + boff + 16384 + rB * 128 + (((kk * 4 + (lane >> 4)) ^ (rB & 7)) * 16));
            }
#pragma unroll
            for (int i = 0; i < 4; ++i)
#pragma unroll
                for (int j = 0; j < 4; ++j)
                    acc[i][j] = __builtin_amdgcn_mfma_f32_16x16x32_bf16(af[i], bfr[j], acc[i][j], 0, 0, 0);
        }
        cur ^= 1;
    }

#pragma unroll
    for (int i = 0; i < 4; ++i) {
        int mrow = wm + i * 16 + (lane >> 4) * 4;
#pragma unroll
        for (int r = 0; r < 4; ++r) {
            int mg = by * BM + mrow + r;
            if (mg < cnt) {
                size_t hrow = (size_t)(off_e + mg) * F;
#pragma unroll
                for (int j = 0; j < 4; ++j) {
                    int ng = n0 + wn + j * 16 + (lane & 15);
                    float v = acc[i][j][r] + b1[e * F + ng];
                    hbuf[hrow + ng] = f2bf(fmaxf(v, 0.f));
                }
            }
        }
    }
}

// ---------------- FFN layer 2: yc[slot] = h @ w2 + b2 (bf16, no atomics) ----------------
__global__ __launch_bounds__(256, 2) void ffn2_kernel(const unsigned short* __restrict__ hbuf,
                                                      const unsigned short* __restrict__ w2t,
                                                      const float* __restrict__ b2,
                                                      const int* __restrict__ counts,
                                                      const int* __restrict__ offs,
                                                      unsigned short* __restrict__ yc) {
    const int orig = blockIdx.x;                 // grid = 4096
    const int logical = (orig & 7) * 512 + (orig >> 3);
    const int e = logical >> 9;
    const int rem = logical & 511;
    const int by = rem >> 3;
    const int bx = rem & 7;
    const int cnt = counts[e];
    if (by * BM >= cnt) return;
    const int n0 = bx * BN;
    const int off_e = offs[e];

    __shared__ __align__(16) char smem[65536];

    const int tid = threadIdx.x;
    const int lane = tid & 63, wid = tid >> 6;
    const int csrc = (lane & 7) ^ (lane >> 3);
    const int rloc = lane >> 3;

    int arow[4];
#pragma unroll
    for (int i = 0; i < 4; ++i) {
        int r = wid * 32 + i * 8 + rloc;
        arow[i] = off_e + min(by * BM + r, cnt - 1);
    }

    floatx4 acc[4][4];
#pragma unroll
    for (int i = 0; i < 4; ++i)
#pragma unroll
        for (int j = 0; j < 4; ++j)
#pragma unroll
            for (int r = 0; r < 4; ++r) acc[i][j][r] = 0.f;

    const int wm = (wid >> 1) * 64, wn = (wid & 1) * 64;

    auto stage = [&](int boff, int kt) {
        const int k0 = kt * BK;
#pragma unroll
        for (int i = 0; i < 4; ++i) {
            int seg = wid * 32 + i * 8;
            gload16(hbuf + (size_t)arow[i] * F + k0 + csrc * 8, smem + boff + seg * 128);
            gload16(w2t + ((size_t)e * H + n0 + seg + rloc) * F + k0 + csrc * 8,
                    smem + boff + 16384 + seg * 128);
        }
    };

    const int NT = F / BK;  // 32
    stage(0, 0);
    int cur = 0;
    for (int kt = 0; kt < NT; ++kt) {
        const int boff = cur * 32768;
        __syncthreads();
        if (kt + 1 < NT) stage(boff ^ 32768, kt + 1);
#pragma unroll
        for (int kk = 0; kk < 2; ++kk) {
            bf16x8 af[4], bfr[4];
#pragma unroll
            for (int i = 0; i < 4; ++i) {
                int rA = wm + i * 16 + (lane & 15);
                af[i] = *(const bf16x8*)(smem + boff + rA * 128 + (((kk * 4 + (lane >> 4)) ^ (rA & 7)) * 16));
                int rB = wn + i * 16 + (lane & 15);
                bfr[i] = *(const bf16x8*)(smem + boff + 16384 + rB * 128 + (((kk * 4 + (lane >> 4)) ^ (rB & 7)) * 16));
            }
#pragma unroll
            for (int i = 0; i < 4; ++i)
#pragma unroll
                for (int j = 0; j < 4; ++j)
                    acc[i][j] = __builtin_amdgcn_mfma_f32_16x16x32_bf16(af[i], bfr[j], acc[i][j], 0, 0, 0);
        }
        cur ^= 1;
    }

#pragma unroll
    for (int i = 0; i < 4; ++i) {
        int mrow = wm + i * 16 + (lane >> 4) * 4;
#pragma unroll
        for (int r = 0; r < 4; ++r) {
            int mg = by * BM + mrow + r;
            if (mg < cnt) {
                size_t yrow = (size_t)(off_e + mg) * H;
#pragma unroll
                for (int j = 0; j < 4; ++j) {
                    int ng = n0 + wn + j * 16 + (lane & 15);
                    yc[yrow + ng] = f2bf(acc[i][j][r] + b2[e * H + ng]);
                }
            }
        }
    }
}

// ---------------- combine: out[t] = w0*yc[slot0] + w1*yc[slot1] ----------------
__global__ __launch_bounds__(256) void combine_kernel(const unsigned short* __restrict__ yc,
                                                      const int* __restrict__ offs,
                                                      const int* __restrict__ inv,
                                                      const float* __restrict__ top_w,
                                                      float* __restrict__ out) {
    const int t = blockIdx.x;
    const int tid = threadIdx.x;
    int c0 = inv[2 * t], c1 = inv[2 * t + 1];
    float w0 = top_w[2 * t], w1 = top_w[2 * t + 1];
    size_t r0 = (size_t)(offs[c0 >> 16] + (c0 & 0xffff)) * H;
    size_t r1 = (size_t)(offs[c1 >> 16] + (c1 & 0xffff)) * H;
    int h = tid * 4;
    ushort4 a = *(const ushort4*)(yc + r0 + h);
    ushort4 b = *(const ushort4*)(yc + r1 + h);
    float4 o;
    o.x = w0 * bf2f(a.x) + w1 * bf2f(b.x);
    o.y = w0 * bf2f(a.y) + w1 * bf2f(b.y);
    o.z = w0 * bf2f(a.z) + w1 * bf2f(b.z);
    o.w = w0 * bf2f(a.w) + w1 * bf2f(b.w);
    *(float4*)(out + (size_t)t * H + h) = o;
}

extern "C" void kernel_launch(void* const* d_in, const int* in_sizes, int n_in,
                              void* d_out, int out_size, void* d_ws, size_t ws_size,
                              hipStream_t stream) {
    (void)in_sizes; (void)n_in; (void)out_size; (void)ws_size;
    const float* x  = (const float*)d_in[0];
    const float* gw = (const float*)d_in[1];
    const float* gb = (const float*)d_in[2];
    const float* w1 = (const float*)d_in[3];
    const float* b1 = (const float*)d_in[4];
    const float* w2 = (const float*)d_in[5];
    const float* b2 = (const float*)d_in[6];
    float* out = (float*)d_out;

    char* ws = (char*)d_ws;
    unsigned short* w2t  = (unsigned short*)(ws);                        // 32 MB @ 0
    unsigned short* hbuf = (unsigned short*)(ws + (32ull << 20));        // 64 MB @ 32
    unsigned short* xb   = (unsigned short*)(ws + (96ull << 20));        // 16 MB @ 96
    unsigned short* w1t  = (unsigned short*)(ws + (112ull << 20));       // 32 MB @ 112 (ends 144)
    // yc overlaps xb+w1t (dead after ffn1): 16384*1024*2B = 32 MB @ 96
    unsigned short* yc   = (unsigned short*)(ws + (96ull << 20));
    char* small = ws + (144ull << 20);
    int*   btok   = (int*)(small);                                       // 256 KB
    float* bwgt   = (float*)(small + 0x40000);                           // 256 KB
    int*   top_i  = (int*)(small + 0x80000);                             // 64 KB
    float* top_w  = (float*)(small + 0x90000);                           // 64 KB
    int*   inv    = (int*)(small + 0xA0000);                             // 64 KB
    int*   counts = (int*)(small + 0xB0000);
    int*   offs   = counts + 8;

    cvt_x_kernel<<<(T_TOK * H / 4) / 256, 256, 0, stream>>>(x, xb);
    transpose_cvt_kernel<<<dim3(F / 32, H / 32, NE), dim3(32, 8), 0, stream>>>(w1, w1t, H, F);
    transpose_cvt_kernel<<<dim3(H / 32, F / 32, NE), dim3(32, 8), 0, stream>>>(w2, w2t, F, H);
    gate_kernel<<<T_TOK / 4, 256, 0, stream>>>(x, gw, gb, top_i, top_w);
    compact_kernel<<<NE, 1024, 0, stream>>>(top_i, top_w, counts, btok, bwgt, inv);
    offsets_kernel<<<1, 64, 0, stream>>>(counts, offs);
    ffn1_kernel<<<16 * 64 * NE, 256, 0, stream>>>(xb, w1t, b1, counts, offs, btok, hbuf);
    ffn2_kernel<<<8 * 64 * NE, 256, 0, stream>>>(hbuf, w2t, b2, counts, offs, yc);
    combine_kernel<<<T_TOK, 256, 0, stream>>>(yc, offs, inv, top_w, out);
}

// Round 5
// 260.194 us; speedup vs baseline: 1.9533x; 1.0084x over previous
//
#include <hip/hip_runtime.h>

#define H 1024
#define F 2048
#define NE 8
#define T_TOK 8192

#define BM 128
#define BN 128
#define BK 64

typedef __bf16 bf16x8 __attribute__((ext_vector_type(8)));
typedef float floatx4 __attribute__((ext_vector_type(4)));

__device__ __forceinline__ unsigned short f2bf(float f) {
    unsigned int u = __builtin_bit_cast(unsigned int, f);
    u = (u + 0x7fffu + ((u >> 16) & 1u)) >> 16;
    return (unsigned short)u;
}
__device__ __forceinline__ float bf2f(unsigned short u) {
    unsigned int x = ((unsigned int)u) << 16;
    return __builtin_bit_cast(float, x);
}

// async 16B global -> LDS (linear dest: wave-uniform base + lane*16)
__device__ __forceinline__ void gload16(const unsigned short* g, void* l) {
    __builtin_amdgcn_global_load_lds(
        (const __attribute__((address_space(1))) unsigned int*)g,
        (__attribute__((address_space(3))) unsigned int*)l,
        16, 0, 0);
}

// ---------------- x fp32 -> bf16 ----------------
__global__ __launch_bounds__(256) void cvt_x_kernel(const float* __restrict__ x,
                                                    unsigned short* __restrict__ xb) {
    int i = blockIdx.x * 256 + threadIdx.x;
    float4 v = ((const float4*)x)[i];
    ushort4 o;
    o.x = f2bf(v.x); o.y = f2bf(v.y); o.z = f2bf(v.z); o.w = f2bf(v.w);
    ((ushort4*)xb)[i] = o;
}

// ---------------- transpose + convert (vectorized): in[R][C] fp32 -> out[C][R] bf16 ----
__global__ __launch_bounds__(256) void transpose_cvt_kernel(const float* __restrict__ in,
                                                            unsigned short* __restrict__ out,
                                                            int R, int C) {
    __shared__ float tile[64][65];
    const size_t mat = (size_t)R * C;
    const float* ib = in + (size_t)blockIdx.z * mat;
    unsigned short* ob = out + (size_t)blockIdx.z * mat;
    int c0 = blockIdx.x * 64, r0 = blockIdx.y * 64;
    int tid = threadIdx.x;
    int tc = tid & 63, tr = tid >> 6;
#pragma unroll
    for (int j = 0; j < 16; ++j)
        tile[tr + j * 4][tc] = ib[(size_t)(r0 + tr + j * 4) * C + c0 + tc];
    __syncthreads();
#pragma unroll
    for (int j = 0; j < 4; ++j) {
        int idx = j * 256 + tid;
        int c = idx >> 4;
        int r4 = (idx & 15) * 4;
        ushort4 o;
        o.x = f2bf(tile[r4 + 0][c]);
        o.y = f2bf(tile[r4 + 1][c]);
        o.z = f2bf(tile[r4 + 2][c]);
        o.w = f2bf(tile[r4 + 3][c]);
        *(ushort4*)(ob + (size_t)(c0 + c) * R + r0 + r4) = o;
    }
}

// ---------------- gating phase A: fp32 logits, per-token top-2 ----------------
__global__ __launch_bounds__(256) void gate_kernel(const float* __restrict__ x,
                                                   const float* __restrict__ gw,
                                                   const float* __restrict__ gb,
                                                   int* __restrict__ top_i,
                                                   float* __restrict__ top_w) {
    const int lane = threadIdx.x & 63;
    const int wid = threadIdx.x >> 6;
    const int t = blockIdx.x * 4 + wid;
    const float* xr = x + (size_t)t * H;
    float acc[8];
#pragma unroll
    for (int e = 0; e < 8; ++e) acc[e] = 0.f;
#pragma unroll
    for (int j = 0; j < 16; ++j) {
        int h = j * 64 + lane;
        float xv = xr[h];
        const float4* g = (const float4*)(gw + h * 8);
        float4 g0 = g[0], g1 = g[1];
        acc[0] += xv * g0.x; acc[1] += xv * g0.y;
        acc[2] += xv * g0.z; acc[3] += xv * g0.w;
        acc[4] += xv * g1.x; acc[5] += xv * g1.y;
        acc[6] += xv * g1.z; acc[7] += xv * g1.w;
    }
#pragma unroll
    for (int m = 32; m >= 1; m >>= 1) {
#pragma unroll
        for (int e = 0; e < 8; ++e) acc[e] += __shfl_xor(acc[e], m, 64);
    }
    if (lane == 0) {
        float lg[8];
#pragma unroll
        for (int e = 0; e < 8; ++e) lg[e] = acc[e] + gb[e];
        int i1 = 0; float v1 = lg[0];
#pragma unroll
        for (int e = 1; e < 8; ++e) { if (lg[e] > v1) { v1 = lg[e]; i1 = e; } }
        int i2 = -1; float v2 = -1e30f;
#pragma unroll
        for (int e = 0; e < 8; ++e) { if (e != i1 && lg[e] > v2) { v2 = lg[e]; i2 = e; } }
        float ed = expf(v2 - v1);
        float wA = 1.f / (1.f + ed);
        float wB = ed / (1.f + ed);
        top_i[t * 2] = i1; top_i[t * 2 + 1] = i2;
        top_w[t * 2] = wA; top_w[t * 2 + 1] = wB;
    }
}

// ---------------- gating phase B: deterministic compaction + inverse map ----------------
__global__ __launch_bounds__(1024) void compact_kernel(const int* __restrict__ top_i,
                                                       const float* __restrict__ top_w,
                                                       int* __restrict__ counts,
                                                       int* __restrict__ btok,
                                                       int* __restrict__ inv) {
    const int e = blockIdx.x;
    const int tid = threadIdx.x;
    const int lane = tid & 63, w = tid >> 6;
    __shared__ int wsums[16];
    int base = 0;
    for (int c = 0; c < T_TOK / 1024; ++c) {
        int t = c * 1024 + tid;
        int i1 = top_i[t * 2], i2 = top_i[t * 2 + 1];
        bool f1 = (i1 == e), f2 = (i2 == e);
        bool f = f1 || f2;
        unsigned long long m = __ballot(f);
        int mypos = __popcll(m & ((1ull << lane) - 1ull));
        if (lane == 0) wsums[w] = __popcll(m);
        __syncthreads();
        int wpre = 0, tot = 0;
#pragma unroll
        for (int i = 0; i < 16; ++i) { int s = wsums[i]; if (i < w) wpre += s; tot += s; }
        if (f) {
            int pos = base + wpre + mypos;
            btok[e * T_TOK + pos] = t;
            inv[t * 2 + (f1 ? 0 : 1)] = (e << 16) | pos;
        }
        base += tot;
        __syncthreads();
    }
    if (tid == 0) counts[e] = base;
}

__global__ void offsets_kernel(const int* __restrict__ counts, int* __restrict__ offs) {
    if (threadIdx.x == 0) {
        int s = 0;
#pragma unroll
        for (int e = 0; e < NE; ++e) { offs[e] = s; s += counts[e]; }
    }
}

// ---------------- FFN layer 1: h = relu(x_gather @ w1 + b1) ----------------
__global__ __launch_bounds__(256, 2) void ffn1_kernel(const unsigned short* __restrict__ xb,
                                                      const unsigned short* __restrict__ w1t,
                                                      const float* __restrict__ b1,
                                                      const int* __restrict__ counts,
                                                      const int* __restrict__ offs,
                                                      const int* __restrict__ btok,
                                                      unsigned short* __restrict__ hbuf) {
    // XCD-chunked: expert == XCD. Within expert: 8x8 super-tiles (4 MB L2 window).
    const int orig = blockIdx.x;                 // grid = 8192
    const int logical = (orig & 7) * 1024 + (orig >> 3);
    const int e = logical >> 10;
    const int rem = logical & 1023;
    const int st = rem >> 6;                     // 16 super-tiles (8 by-rows x 8 bx-cols)
    const int iy = (rem >> 3) & 7, ix = rem & 7;
    const int by = (st >> 1) * 8 + iy;           // 0..63
    const int bx = (st & 1) * 8 + ix;            // 0..15
    const int cnt = counts[e];
    if (by * BM >= cnt) return;
    const int n0 = bx * BN;
    const int off_e = offs[e];

    __shared__ __align__(16) char smem[65536];

    const int tid = threadIdx.x;
    const int lane = tid & 63, wid = tid >> 6;
    const int csrc = (lane & 7) ^ (lane >> 3);   // pre-swizzled source chunk
    const int rloc = lane >> 3;                  // row within 8-row segment

    int tokA[4];
#pragma unroll
    for (int i = 0; i < 4; ++i) {
        int r = wid * 32 + i * 8 + rloc;
        tokA[i] = btok[e * T_TOK + min(by * BM + r, cnt - 1)];
    }

    floatx4 acc[4][4];
#pragma unroll
    for (int i = 0; i < 4; ++i)
#pragma unroll
        for (int j = 0; j < 4; ++j)
#pragma unroll
            for (int r = 0; r < 4; ++r) acc[i][j][r] = 0.f;

    const int wm = (wid >> 1) * 64, wn = (wid & 1) * 64;

    auto stage = [&](int boff, int kt) {
        const int k0 = kt * BK;
#pragma unroll
        for (int i = 0; i < 4; ++i) {
            int seg = wid * 32 + i * 8;
            gload16(xb + (size_t)tokA[i] * H + k0 + csrc * 8, smem + boff + seg * 128);
            gload16(w1t + ((size_t)e * F + n0 + seg + rloc) * H + k0 + csrc * 8,
                    smem + boff + 16384 + seg * 128);
        }
    };

    const int NT = H / BK;  // 16
    stage(0, 0);
    stage(32768, 1);
#pragma unroll 1
    for (int kt = 0; kt < NT; ++kt) {
        const int boff = (kt & 1) * 32768;
        if (kt < NT - 1) asm volatile("s_waitcnt vmcnt(8)" ::: "memory");
        else             asm volatile("s_waitcnt vmcnt(0)" ::: "memory");
        __builtin_amdgcn_s_barrier();            // tile kt fully in LDS (all waves)
        __builtin_amdgcn_sched_barrier(0);
#pragma unroll
        for (int kk = 0; kk < 2; ++kk) {
            bf16x8 af[4], bfr[4];
#pragma unroll
            for (int i = 0; i < 4; ++i) {
                int rA = wm + i * 16 + (lane & 15);
                af[i] = *(const bf16x8*)(smem + boff + rA * 128 + (((kk * 4 + (lane >> 4)) ^ (rA & 7)) * 16));
                int rB = wn + i * 16 + (lane & 15);
                bfr[i] = *(const bf16x8*)(smem + boff + 16384 + rB * 128 + (((kk * 4 + (lane >> 4)) ^ (rB & 7)) * 16));
            }
#pragma unroll
            for (int i = 0; i < 4; ++i)
#pragma unroll
                for (int j = 0; j < 4; ++j)
                    acc[i][j] = __builtin_amdgcn_mfma_f32_16x16x32_bf16(af[i], bfr[j], acc[i][j], 0, 0, 0);
        }
        __builtin_amdgcn_sched_barrier(0);
        __builtin_amdgcn_s_barrier();            // all waves done reading buf[kt&1]
        __builtin_amdgcn_sched_barrier(0);
        if (kt + 2 < NT) stage(boff, kt + 2);    // refill just-consumed buffer
    }

#pragma unroll
    for (int i = 0; i < 4; ++i) {
        int mrow = wm + i * 16 + (lane >> 4) * 4;
#pragma unroll
        for (int r = 0; r < 4; ++r) {
            int mg = by * BM + mrow + r;
            if (mg < cnt) {
                size_t hrow = (size_t)(off_e + mg) * F;
#pragma unroll
                for (int j = 0; j < 4; ++j) {
                    int ng = n0 + wn + j * 16 + (lane & 15);
                    float v = acc[i][j][r] + b1[e * F + ng];
                    hbuf[hrow + ng] = f2bf(fmaxf(v, 0.f));
                }
            }
        }
    }
}

// ---------------- FFN layer 2: yc[slot] = h @ w2 + b2 (bf16, no atomics) ----------------
__global__ __launch_bounds__(256, 2) void ffn2_kernel(const unsigned short* __restrict__ hbuf,
                                                      const unsigned short* __restrict__ w2t,
                                                      const float* __restrict__ b2,
                                                      const int* __restrict__ counts,
                                                      const int* __restrict__ offs,
                                                      unsigned short* __restrict__ yc) {
    const int orig = blockIdx.x;                 // grid = 4096
    const int logical = (orig & 7) * 512 + (orig >> 3);
    const int e = logical >> 9;
    const int rem = logical & 511;
    const int by = rem >> 3;
    const int bx = rem & 7;
    const int cnt = counts[e];
    if (by * BM >= cnt) return;
    const int n0 = bx * BN;
    const int off_e = offs[e];

    __shared__ __align__(16) char smem[65536];

    const int tid = threadIdx.x;
    const int lane = tid & 63, wid = tid >> 6;
    const int csrc = (lane & 7) ^ (lane >> 3);
    const int rloc = lane >> 3;

    int arow[4];
#pragma unroll
    for (int i = 0; i < 4; ++i) {
        int r = wid * 32 + i * 8 + rloc;
        arow[i] = off_e + min(by * BM + r, cnt - 1);
    }

    floatx4 acc[4][4];
#pragma unroll
    for (int i = 0; i < 4; ++i)
#pragma unroll
        for (int j = 0; j < 4; ++j)
#pragma unroll
            for (int r = 0; r < 4; ++r) acc[i][j][r] = 0.f;

    const int wm = (wid >> 1) * 64, wn = (wid & 1) * 64;

    auto stage = [&](int boff, int kt) {
        const int k0 = kt * BK;
#pragma unroll
        for (int i = 0; i < 4; ++i) {
            int seg = wid * 32 + i * 8;
            gload16(hbuf + (size_t)arow[i] * F + k0 + csrc * 8, smem + boff + seg * 128);
            gload16(w2t + ((size_t)e * H + n0 + seg + rloc) * F + k0 + csrc * 8,
                    smem + boff + 16384 + seg * 128);
        }
    };

    const int NT = F / BK;  // 32
    stage(0, 0);
    stage(32768, 1);
#pragma unroll 1
    for (int kt = 0; kt < NT; ++kt) {
        const int boff = (kt & 1) * 32768;
        if (kt < NT - 1) asm volatile("s_waitcnt vmcnt(8)" ::: "memory");
        else             asm volatile("s_waitcnt vmcnt(0)" ::: "memory");
        __builtin_amdgcn_s_barrier();
        __builtin_amdgcn_sched_barrier(0);
#pragma unroll
        for (int kk = 0; kk < 2; ++kk) {
            bf16x8 af[4], bfr[4];
#pragma unroll
            for (int i = 0; i < 4; ++i) {
                int rA = wm + i * 16 + (lane & 15);
                af[i] = *(const bf16x8*)(smem + boff + rA * 128 + (((kk * 4 + (lane >> 4)) ^ (rA & 7)) * 16));
                int rB = wn + i * 16 + (lane & 15);
                bfr[i] = *(const bf16x8*)(smem + boff + 16384 + rB * 128 + (((kk * 4 + (lane >> 4)) ^ (rB & 7)) * 16));
            }
#pragma unroll
            for (int i = 0; i < 4; ++i)
#pragma unroll
                for (int j = 0; j < 4; ++j)
                    acc[i][j] = __builtin_amdgcn_mfma_f32_16x16x32_bf16(af[i], bfr[j], acc[i][j], 0, 0, 0);
        }
        __builtin_amdgcn_sched_barrier(0);
        __builtin_amdgcn_s_barrier();
        __builtin_amdgcn_sched_barrier(0);
        if (kt + 2 < NT) stage(boff, kt + 2);
    }

#pragma unroll
    for (int i = 0; i < 4; ++i) {
        int mrow = wm + i * 16 + (lane >> 4) * 4;
#pragma unroll
        for (int r = 0; r < 4; ++r) {
            int mg = by * BM + mrow + r;
            if (mg < cnt) {
                size_t yrow = (size_t)(off_e + mg) * H;
#pragma unroll
                for (int j = 0; j < 4; ++j) {
                    int ng = n0 + wn + j * 16 + (lane & 15);
                    yc[yrow + ng] = f2bf(acc[i][j][r] + b2[e * H + ng]);
                }
            }
        }
    }
}

// ---------------- combine: out[t] = w0*yc[slot0] + w1*yc[slot1] ----------------
__global__ __launch_bounds__(256) void combine_kernel(const unsigned short* __restrict__ yc,
                                                      const int* __restrict__ offs,
                                                      const int* __restrict__ inv,
                                                      const float* __restrict__ top_w,
                                                      float* __restrict__ out) {
    const int t = blockIdx.x;
    const int tid = threadIdx.x;
    int c0 = inv[2 * t], c1 = inv[2 * t + 1];
    float w0 = top_w[2 * t], w1 = top_w[2 * t + 1];
    size_t r0 = (size_t)(offs[c0 >> 16] + (c0 & 0xffff)) * H;
    size_t r1 = (size_t)(offs[c1 >> 16] + (c1 & 0xffff)) * H;
    int h = tid * 4;
    ushort4 a = *(const ushort4*)(yc + r0 + h);
    ushort4 b = *(const ushort4*)(yc + r1 + h);
    float4 o;
    o.x = w0 * bf2f(a.x) + w1 * bf2f(b.x);
    o.y = w0 * bf2f(a.y) + w1 * bf2f(b.y);
    o.z = w0 * bf2f(a.z) + w1 * bf2f(b.z);
    o.w = w0 * bf2f(a.w) + w1 * bf2f(b.w);
    *(float4*)(out + (size_t)t * H + h) = o;
}

extern "C" void kernel_launch(void* const* d_in, const int* in_sizes, int n_in,
                              void* d_out, int out_size, void* d_ws, size_t ws_size,
                              hipStream_t stream) {
    (void)in_sizes; (void)n_in; (void)out_size; (void)ws_size;
    const float* x  = (const float*)d_in[0];
    const float* gw = (const float*)d_in[1];
    const float* gb = (const float*)d_in[2];
    const float* w1 = (const float*)d_in[3];
    const float* b1 = (const float*)d_in[4];
    const float* w2 = (const float*)d_in[5];
    const float* b2 = (const float*)d_in[6];
    float* out = (float*)d_out;

    char* ws = (char*)d_ws;
    unsigned short* w2t  = (unsigned short*)(ws);                        // 32 MB @ 0
    unsigned short* hbuf = (unsigned short*)(ws + (32ull << 20));        // 64 MB @ 32
    unsigned short* xb   = (unsigned short*)(ws + (96ull << 20));        // 16 MB @ 96
    unsigned short* w1t  = (unsigned short*)(ws + (112ull << 20));       // 32 MB @ 112 (ends 144)
    // yc overlaps xb+w1t (dead after ffn1): 16384*1024*2B = 32 MB @ 96
    unsigned short* yc   = (unsigned short*)(ws + (96ull << 20));
    char* small = ws + (144ull << 20);
    int*   btok   = (int*)(small);                                       // 256 KB
    int*   top_i  = (int*)(small + 0x80000);                             // 64 KB
    float* top_w  = (float*)(small + 0x90000);                           // 64 KB
    int*   inv    = (int*)(small + 0xA0000);                             // 64 KB
    int*   counts = (int*)(small + 0xB0000);
    int*   offs   = counts + 8;

    cvt_x_kernel<<<(T_TOK * H / 4) / 256, 256, 0, stream>>>(x, xb);
    transpose_cvt_kernel<<<dim3(F / 64, H / 64, NE), 256, 0, stream>>>(w1, w1t, H, F);
    transpose_cvt_kernel<<<dim3(H / 64, F / 64, NE), 256, 0, stream>>>(w2, w2t, F, H);
    gate_kernel<<<T_TOK / 4, 256, 0, stream>>>(x, gw, gb, top_i, top_w);
    compact_kernel<<<NE, 1024, 0, stream>>>(top_i, top_w, counts, btok, inv);
    offsets_kernel<<<1, 64, 0, stream>>>(counts, offs);
    ffn1_kernel<<<16 * 64 * NE, 256, 0, stream>>>(xb, w1t, b1, counts, offs, btok, hbuf);
    ffn2_kernel<<<8 * 64 * NE, 256, 0, stream>>>(hbuf, w2t, b2, counts, offs, yc);
    combine_kernel<<<T_TOK, 256, 0, stream>>>(yc, offs, inv, top_w, out);
}